// Round 1
// baseline (18726.070 us; speedup 1.0000x reference)
//
#include <hip/hip_runtime.h>
#include <hip/hip_bf16.h>
#include <math.h>

// Problem constants
#define TY 128
#define B  64
#define TX 400
#define IN 512
#define H  512
#define C  512
#define NH 8
#define DH 64
#define G4 2048   // 4*H

__device__ __forceinline__ float sigf(float x) { return 1.f / (1.f + __expf(-x)); }

// ---------------------------------------------------------------------------
// Generic tiled GEMM: Out[r,n] = sum_k A[r,k]*W[n,k] + bias1[n] (+bias2[n])
// A row-major [R,K], W row-major [N,K]. grid = (N/64, R/64), 256 threads.
// ---------------------------------------------------------------------------
__global__ __launch_bounds__(256) void gemm_bias(
    const float* __restrict__ A, const float* __restrict__ W,
    const float* __restrict__ bias1, const float* __restrict__ bias2,
    float* __restrict__ Out, int N, int K) {
  __shared__ float As[16][68];
  __shared__ float Ws[16][68];
  int tid = threadIdx.x;
  int n0 = blockIdx.x * 64;
  int r0 = blockIdx.y * 64;
  int tx = tid & 15, ty = tid >> 4;
  float acc[4][4] = {};
  for (int k0 = 0; k0 < K; k0 += 16) {
    #pragma unroll
    for (int i = 0; i < 4; i++) {
      int idx = tid + i * 256;          // 0..1023
      int r = idx >> 4, k = idx & 15;
      As[k][r] = A[(size_t)(r0 + r) * K + k0 + k];
      Ws[k][r] = W[(size_t)(n0 + r) * K + k0 + k];
    }
    __syncthreads();
    #pragma unroll
    for (int k = 0; k < 16; k++) {
      float a[4], w[4];
      #pragma unroll
      for (int i = 0; i < 4; i++) a[i] = As[k][ty * 4 + i];
      #pragma unroll
      for (int j = 0; j < 4; j++) w[j] = Ws[k][tx * 4 + j];
      #pragma unroll
      for (int i = 0; i < 4; i++)
        #pragma unroll
        for (int j = 0; j < 4; j++) acc[i][j] += a[i] * w[j];
    }
    __syncthreads();
  }
  #pragma unroll
  for (int i = 0; i < 4; i++) {
    int r = r0 + ty * 4 + i;
    #pragma unroll
    for (int j = 0; j < 4; j++) {
      int n = n0 + tx * 4 + j;
      float v = acc[i][j];
      if (bias1) v += bias1[n];
      if (bias2) v += bias2[n];
      Out[(size_t)r * N + n] = v;
    }
  }
}

// ---------------------------------------------------------------------------
// Split-K GEMM for the per-step small GEMMs (R = 64 batch rows).
// P[s][b][n] = sum_{k in slice s} A(b,k) * W[n,k]
// A(b,k) = k<512 ? A1[b*512+k] : A2[b*512+k-512]
// grid = (N/64, numSlices); KS = slice length; Ktot = W row stride.
// ---------------------------------------------------------------------------
__global__ __launch_bounds__(256) void gemm_split(
    const float* __restrict__ A1, const float* __restrict__ A2,
    const float* __restrict__ W, float* __restrict__ P,
    int N, int Ktot, int KS) {
  __shared__ float As[16][68];
  __shared__ float Ws[16][68];
  int tid = threadIdx.x;
  int n0 = blockIdx.x * 64;
  int kbeg = blockIdx.y * KS;
  int tx = tid & 15, ty = tid >> 4;
  float acc[4][4] = {};
  for (int k0 = kbeg; k0 < kbeg + KS; k0 += 16) {
    #pragma unroll
    for (int i = 0; i < 4; i++) {
      int idx = tid + i * 256;
      int r = idx >> 4, kk = k0 + (idx & 15);
      float av = (kk < 512) ? A1[r * 512 + kk] : A2[r * 512 + kk - 512];
      As[idx & 15][r] = av;
      Ws[idx & 15][r] = W[(size_t)(n0 + r) * Ktot + kk];
    }
    __syncthreads();
    #pragma unroll
    for (int k = 0; k < 16; k++) {
      float a[4], w[4];
      #pragma unroll
      for (int i = 0; i < 4; i++) a[i] = As[k][ty * 4 + i];
      #pragma unroll
      for (int j = 0; j < 4; j++) w[j] = Ws[k][tx * 4 + j];
      #pragma unroll
      for (int i = 0; i < 4; i++)
        #pragma unroll
        for (int j = 0; j < 4; j++) acc[i][j] += a[i] * w[j];
    }
    __syncthreads();
  }
  float* Pp = P + (size_t)blockIdx.y * 64 * N;
  #pragma unroll
  for (int i = 0; i < 4; i++) {
    int b = ty * 4 + i;
    #pragma unroll
    for (int j = 0; j < 4; j++) {
      Pp[b * N + n0 + tx * 4 + j] = acc[i][j];
    }
  }
}

// ---------------------------------------------------------------------------
// LSTM cell: gates = xW (has x@Wih + b_ih + b_hh) + sum_s gatesP ; nonlins,
// mask, write h1 -> hs & ss, c1 -> cs. 32768 threads.
// ---------------------------------------------------------------------------
__global__ __launch_bounds__(256) void k_cell(
    const float* __restrict__ xW, const float* __restrict__ gatesP,
    const float* __restrict__ hprev, const float* __restrict__ cprev,
    const float* __restrict__ ymask,
    float* __restrict__ hs_out, float* __restrict__ ss_out,
    float* __restrict__ cs_out) {
  int idx = blockIdx.x * 256 + threadIdx.x;   // 0..32767
  int b = idx >> 9, m = idx & 511;
  float g4[4];
  #pragma unroll
  for (int q = 0; q < 4; q++) {
    int j = q * 512 + m;
    float g = xW[b * 2048 + j];
    #pragma unroll
    for (int s = 0; s < 8; s++) g += gatesP[(s * 64 + b) * 2048 + j];
    g4[q] = g;
  }
  float i_ = sigf(g4[0]);
  float f_ = sigf(g4[1]);
  float gg = tanhf(g4[2]);
  float o_ = sigf(g4[3]);
  float cp = cprev[idx], hp = hprev[idx];
  float c1 = f_ * cp + i_ * gg;
  float h1 = o_ * tanhf(c1);
  float ym = ymask[b];
  h1 = ym * h1 + (1.f - ym) * hp;
  c1 = ym * c1 + (1.f - ym) * cp;
  hs_out[idx] = h1;
  ss_out[idx] = h1;
  cs_out[idx] = c1;
}

// Reduce hq partials: hq[idx] = sum_s hqP[s*32768 + idx]
__global__ __launch_bounds__(256) void k_hq_reduce(
    const float* __restrict__ hqP, float* __restrict__ hq) {
  int idx = blockIdx.x * 256 + threadIdx.x;   // 0..32767
  float v = 0.f;
  #pragma unroll
  for (int s = 0; s < 8; s++) v += hqP[s * 32768 + idx];
  hq[idx] = v;
}

// ---------------------------------------------------------------------------
// e[b][h][t] = xm * sum_d tanh(pctx[t,b,h*64+d] + hq[b,...] + acc[b,t]*Wcov) * U[h,d]
// One wave per (t,b) pair. grid = TX*B/4 blocks of 256.
// ---------------------------------------------------------------------------
__global__ __launch_bounds__(256) void k_e(
    const float* __restrict__ pctx, const float* __restrict__ hq,
    const float* __restrict__ acc, const float* __restrict__ Wcov,
    const float* __restrict__ U, const float* __restrict__ x_mask,
    float* __restrict__ e) {
  int wv = threadIdx.x >> 6, lane = threadIdx.x & 63;
  int pair = blockIdx.x * 4 + wv;             // t*B + b
  int t = pair >> 6, b = pair & 63;
  const float* prow = pctx + (size_t)pair * 512;
  float a = acc[b * TX + t];
  float xm = x_mask[pair];
  float v[8];
  #pragma unroll
  for (int h = 0; h < 8; h++) {
    int c = h * 64 + lane;
    float u = tanhf(prow[c] + hq[b * 512 + c] + a * Wcov[c]);
    v[h] = u * U[h * 64 + lane];
  }
  #pragma unroll
  for (int off = 32; off; off >>= 1)
    #pragma unroll
    for (int h = 0; h < 8; h++) v[h] += __shfl_xor(v[h], off);
  if (lane == 0) {
    float* ep = e + (b * 8) * TX + t;
    #pragma unroll
    for (int h = 0; h < 8; h++) ep[h * TX] = v[h] * xm;
  }
}

// ---------------------------------------------------------------------------
// Softmax over t per (b,h); writes w; for h==0 also dist, Cs (pre-update acc),
// and acc += w. grid = B*NH blocks of 256.
// ---------------------------------------------------------------------------
__global__ __launch_bounds__(256) void k_softmax(
    const float* __restrict__ e, const float* __restrict__ x_mask,
    float* __restrict__ w, float* __restrict__ acc,
    float* __restrict__ dist_out, float* __restrict__ Cs_out) {
  int bh = blockIdx.x;
  int b = bh >> 3, h = bh & 7;
  const float* erow = e + bh * TX;
  float* wrow = w + bh * TX;
  int tid = threadIdx.x;
  int wv = tid >> 6, lane = tid & 63;
  __shared__ float sm[4], ssum[4];
  float e0 = (tid < TX) ? erow[tid] : -1e30f;
  float e1 = (tid + 256 < TX) ? erow[tid + 256] : -1e30f;
  float m = fmaxf(e0, e1);
  #pragma unroll
  for (int off = 32; off; off >>= 1) m = fmaxf(m, __shfl_xor(m, off));
  if (lane == 0) sm[wv] = m;
  __syncthreads();
  m = fmaxf(fmaxf(sm[0], sm[1]), fmaxf(sm[2], sm[3]));
  float xm0 = (tid < TX) ? x_mask[tid * 64 + b] : 0.f;
  float xm1 = (tid + 256 < TX) ? x_mask[(tid + 256) * 64 + b] : 0.f;
  float w0 = (tid < TX) ? __expf(e0 - m) * xm0 : 0.f;
  float w1 = (tid + 256 < TX) ? __expf(e1 - m) * xm1 : 0.f;
  float s = w0 + w1;
  #pragma unroll
  for (int off = 32; off; off >>= 1) s += __shfl_xor(s, off);
  if (lane == 0) ssum[wv] = s;
  __syncthreads();
  s = ssum[0] + ssum[1] + ssum[2] + ssum[3] + 1e-6f;
  float inv = 1.f / s;
  w0 *= inv; w1 *= inv;
  if (tid < TX) wrow[tid] = w0;
  if (tid + 256 < TX) wrow[tid + 256] = w1;
  if (h == 0) {
    if (tid < TX) {
      float a = acc[b * TX + tid];
      dist_out[b * TX + tid] = w0;
      Cs_out[b * TX + tid] = a;
      acc[b * TX + tid] = a + w0;
    }
    if (tid + 256 < TX) {
      float a = acc[b * TX + tid + 256];
      dist_out[b * TX + tid + 256] = w1;
      Cs_out[b * TX + tid + 256] = a;
      acc[b * TX + tid + 256] = a + w1;
    }
  }
}

// ---------------------------------------------------------------------------
// att[b, h*64+d] = sum_t w[b][h][t] * pv[t][b][h*64+d]. grid = B*NH blocks.
// ---------------------------------------------------------------------------
__global__ __launch_bounds__(256) void k_att(
    const float* __restrict__ w, const float* __restrict__ pv,
    float* __restrict__ att) {
  int bh = blockIdx.x;
  int b = bh >> 3, h = bh & 7;
  int wv = threadIdx.x >> 6, lane = threadIdx.x & 63;
  const float* wrow = w + bh * TX;
  float p = 0.f;
  for (int t = wv; t < TX; t += 4) {
    p += wrow[t] * pv[((size_t)(t * 64 + b) * 8 + h) * 64 + lane];
  }
  __shared__ float buf[4][64];
  buf[wv][lane] = p;
  __syncthreads();
  if (wv == 0) {
    float v = buf[0][lane] + buf[1][lane] + buf[2][lane] + buf[3][lane];
    att[b * 512 + h * 64 + lane] = v;
  }
}

// ---------------------------------------------------------------------------
// att2 = att @ W_concat^T, then LayerNorm, write atts output. block per b.
// ---------------------------------------------------------------------------
__global__ __launch_bounds__(256) void k_concat_ln(
    const float* __restrict__ att, const float* __restrict__ Wcat,
    const float* __restrict__ ln_g, const float* __restrict__ ln_b,
    float* __restrict__ atts_out) {
  int b = blockIdx.x;
  int tid = threadIdx.x;
  int wv = tid >> 6, lane = tid & 63;
  __shared__ float s_att[512];
  __shared__ float s_o[512];
  __shared__ float rs[4], rq[4];
  s_att[tid] = att[b * 512 + tid];
  s_att[tid + 256] = att[b * 512 + tid + 256];
  __syncthreads();
  for (int j = wv; j < 512; j += 4) {
    const float* wr = Wcat + (size_t)j * 512;
    float p = 0.f;
    #pragma unroll
    for (int q = 0; q < 8; q++) p += s_att[q * 64 + lane] * wr[q * 64 + lane];
    #pragma unroll
    for (int off = 32; off; off >>= 1) p += __shfl_xor(p, off);
    if (lane == 0) s_o[j] = p;
  }
  __syncthreads();
  float x0 = s_o[tid], x1 = s_o[tid + 256];
  float sum = x0 + x1, sq = x0 * x0 + x1 * x1;
  #pragma unroll
  for (int off = 32; off; off >>= 1) {
    sum += __shfl_xor(sum, off);
    sq += __shfl_xor(sq, off);
  }
  if (lane == 0) { rs[wv] = sum; rq[wv] = sq; }
  __syncthreads();
  sum = rs[0] + rs[1] + rs[2] + rs[3];
  sq = rq[0] + rq[1] + rq[2] + rq[3];
  float mu = sum * (1.f / 512.f);
  float var = sq * (1.f / 512.f) - mu * mu;
  float rstd = rsqrtf(var + 1e-5f);
  atts_out[b * 512 + tid] = (x0 - mu) * rstd * ln_g[tid] + ln_b[tid];
  atts_out[b * 512 + tid + 256] = (x1 - mu) * rstd * ln_g[tid + 256] + ln_b[tid + 256];
}

// acc <- init_coverage
__global__ __launch_bounds__(256) void k_init_acc(
    const float* __restrict__ ic, float* __restrict__ acc) {
  int idx = blockIdx.x * 256 + threadIdx.x;
  if (idx < B * TX) acc[idx] = ic[idx];
}

// ---------------------------------------------------------------------------
extern "C" void kernel_launch(void* const* d_in, const int* in_sizes, int n_in,
                              void* d_out, int out_size, void* d_ws, size_t ws_size,
                              hipStream_t stream) {
  const float* y_emb    = (const float*)d_in[0];
  const float* context  = (const float*)d_in[1];
  const float* h0       = (const float*)d_in[2];
  const float* c0       = (const float*)d_in[3];
  const float* x_mask   = (const float*)d_in[4];
  const float* y_mask   = (const float*)d_in[5];
  const float* init_cov = (const float*)d_in[6];
  const float* W_ih     = (const float*)d_in[7];
  const float* W_hh     = (const float*)d_in[8];
  const float* b_ih     = (const float*)d_in[9];
  const float* b_hh     = (const float*)d_in[10];
  const float* Wc_att   = (const float*)d_in[11];
  const float* b_att    = (const float*)d_in[12];
  const float* Wv_att   = (const float*)d_in[13];
  const float* bv_att   = (const float*)d_in[14];
  const float* W_comb   = (const float*)d_in[15];
  const float* U_att    = (const float*)d_in[16];
  const float* W_cov    = (const float*)d_in[17];
  const float* W_cat    = (const float*)d_in[18];
  const float* ln_g     = (const float*)d_in[19];
  const float* ln_b     = (const float*)d_in[20];

  float* out = (float*)d_out;
  const size_t SZ_H = (size_t)TY * B * H;     // 4,194,304
  const size_t SZ_D = (size_t)TY * B * TX;    // 3,276,800
  float* hs    = out;
  float* cs    = out + SZ_H;
  float* ss    = out + 2 * SZ_H;
  float* atts  = out + 3 * SZ_H;
  float* dists = out + 4 * SZ_H;
  float* Cs    = out + 4 * SZ_H + SZ_D;

  float* ws = (float*)d_ws;
  size_t off = 0;
  float* pctx   = ws + off; off += (size_t)TX * B * C;       // 13,107,200
  float* pv     = ws + off; off += (size_t)TX * B * C;       // 13,107,200
  float* xW     = ws + off; off += (size_t)TY * B * G4;      // 16,777,216
  float* gatesP = ws + off; off += (size_t)8 * B * G4;       // 1,048,576
  float* hqP    = ws + off; off += (size_t)8 * B * C;        // 262,144
  float* hq     = ws + off; off += (size_t)B * C;            // 32,768
  float* ebuf   = ws + off; off += (size_t)B * NH * TX;      // 204,800
  float* wbuf   = ws + off; off += (size_t)B * NH * TX;      // 204,800
  float* attbuf = ws + off; off += (size_t)B * C;            // 32,768
  float* accbuf = ws + off; off += (size_t)B * TX;           // 25,600

  // ---- precompute ----
  gemm_bias<<<dim3(C / 64, TX * B / 64), 256, 0, stream>>>(
      context, Wc_att, b_att, nullptr, pctx, C, C);
  gemm_bias<<<dim3(C / 64, TX * B / 64), 256, 0, stream>>>(
      context, Wv_att, bv_att, nullptr, pv, C, C);
  gemm_bias<<<dim3(G4 / 64, TY * B / 64), 256, 0, stream>>>(
      y_emb, W_ih, b_ih, b_hh, xW, G4, IN);
  k_init_acc<<<(B * TX + 255) / 256, 256, 0, stream>>>(init_cov, accbuf);

  // ---- sequential steps ----
  for (int t = 0; t < TY; t++) {
    const float* hp = (t == 0) ? h0 : hs + (size_t)(t - 1) * B * H;
    const float* cp = (t == 0) ? c0 : cs + (size_t)(t - 1) * B * H;
    float* hs_t = hs + (size_t)t * B * H;
    float* cs_t = cs + (size_t)t * B * H;
    float* ss_t = ss + (size_t)t * B * H;

    // gates partials: h_prev @ W_hh^T   (N=2048, K=512, 8 slices of 64)
    gemm_split<<<dim3(G4 / 64, 8), 256, 0, stream>>>(
        hp, nullptr, W_hh, gatesP, G4, 512, 64);
    k_cell<<<B * H / 256, 256, 0, stream>>>(
        xW + (size_t)t * B * G4, gatesP, hp, cp, y_mask + (size_t)t * B,
        hs_t, ss_t, cs_t);
    // hq partials: [h1,c1] @ W_comb^T   (N=512, K=1024, 8 slices of 128)
    gemm_split<<<dim3(C / 64, 8), 256, 0, stream>>>(
        hs_t, cs_t, W_comb, hqP, C, 1024, 128);
    k_hq_reduce<<<B * C / 256, 256, 0, stream>>>(hqP, hq);
    // e scores
    k_e<<<TX * B / 4, 256, 0, stream>>>(
        pctx, hq, accbuf, W_cov, U_att, x_mask, ebuf);
    // softmax + dist + Cs + coverage update
    k_softmax<<<B * NH, 256, 0, stream>>>(
        ebuf, x_mask, wbuf, accbuf,
        dists + (size_t)t * B * TX, Cs + (size_t)t * B * TX);
    // attention-weighted sum of pv
    k_att<<<B * NH, 256, 0, stream>>>(wbuf, pv, attbuf);
    // concat projection + LayerNorm
    k_concat_ln<<<B, 256, 0, stream>>>(
        attbuf, W_cat, ln_g, ln_b, atts + (size_t)t * B * C);
  }
}